// Round 14
// baseline (43.222 us; speedup 1.0000x reference)
//
#include <hip/hip_runtime.h>

// Grayscale morphological dilation, 7x7 additive SE, zero 'same' padding:
//   out[p, i, j] = max_{a,b in 0..6} ( xz(p, i+a-3, j+b-3) + w[a,b] )
//
// R14 = R7 geometry (8-wide x 8-tall thread tile -- highest measured
// VALUBusy 74-83%) + R9 pk_add core + R8 max3 tree. Rationale from
// R7-R13 fits: dur ~= VALU_issue/VALUBusy at ~1.33GHz sustained; 8-wide
// halves VMEM-per-output (56 loads/64 out = 0.875 vs R8's 1.56) AND
// pk_add halves the adds -> both the VALU and memory terms shrink, and
// the longer per-row compute (2x R8) restores R7-grade latency hiding.
// Block 256 = 32 thread-cols x 8 thread-rows -> tile 256x64; grid
// (2,8,64) = 1024 blocks = 4 blocks/CU, ~4 waves/SIMD at ~120 VGPR.
// Per-lane guards (R7 style): row-OOB and the 2 edge chunks cndmask to a
// 16B zero page; middle 2 chunks always in-bounds. Literal indices only.

#define HH 512
#define WW 512

typedef float v2f __attribute__((ext_vector_type(2)));

__device__ __align__(16) const float ZROW[16] = {};  // zero page

__device__ __forceinline__ float max3f(float a, float b, float c) {
  float d;
  asm("v_max3_f32 %0, %1, %2, %3" : "=v"(d) : "v"(a), "v"(b), "v"(c));
  return d;
}

// E[p] = (rvf[2p], rvf[2p+1]), rvf[i] = input col col0-4+i, i = 0..15.
#define LOADROW(E, K)                                                        \
  {                                                                          \
    const int r_ = row0 - 3 + (K);                                           \
    const bool rok_ = ((unsigned)r_ < (unsigned)HH);                         \
    const float* rp_ = xp + (ptrdiff_t)r_ * WW + (col0 - 4);                 \
    const float* p0_ = (rok_ && okL) ? rp_ : zp;                             \
    const float* p1_ = rok_ ? rp_ + 4 : zp;                                  \
    const float* p2_ = rok_ ? rp_ + 8 : zp;                                  \
    const float* p3_ = (rok_ && okR) ? rp_ + 12 : zp;                        \
    float4 v0_ = *reinterpret_cast<const float4*>(p0_);                      \
    float4 v1_ = *reinterpret_cast<const float4*>(p1_);                      \
    float4 v2_ = *reinterpret_cast<const float4*>(p2_);                      \
    float4 v3_ = *reinterpret_cast<const float4*>(p3_);                      \
    E[0] = (v2f){v0_.x, v0_.y};  E[1] = (v2f){v0_.z, v0_.w};                 \
    E[2] = (v2f){v1_.x, v1_.y};  E[3] = (v2f){v1_.z, v1_.w};                 \
    E[4] = (v2f){v2_.x, v2_.y};  E[5] = (v2f){v2_.z, v2_.w};                 \
    E[6] = (v2f){v3_.x, v3_.y};  E[7] = (v2f){v3_.z, v3_.w};                 \
  }

// Output j uses rvf[j+1 .. j+7]; tap pairs (b,b+1) at bases j+1, j+3, j+5
// and scalar tail rvf[j+7].
#define ONEOUT(T, K, J, P1, P2, P3, S)                                       \
  {                                                                          \
    const int a_ = (K) - (T);                                                \
    const v2f c01_ = (P1) + w2[a_][0];          /* v_pk_add_f32 */           \
    const v2f c23_ = (P2) + w2[a_][1];                                       \
    const v2f c45_ = (P3) + w2[a_][2];                                       \
    const float c6_ = (S) + w6[a_];                                          \
    const float t1_ = max3f(c01_.x, c01_.y, c23_.x);                         \
    const float t2_ = max3f(c23_.y, c45_.x, c45_.y);                         \
    acc[T][J] = ((K) == (T))                                                 \
                    ? max3f(t1_, t2_, c6_)               /* first touch */   \
                    : max3f(t1_, t2_, fmaxf(c6_, acc[T][J]));                \
  }

// K literal at every expansion site; all indices fold at compile time.
#define COMPROW(E, K)                                                        \
  {                                                                          \
    const v2f o0_ = (v2f){E[0].y, E[1].x};                                   \
    const v2f o1_ = (v2f){E[1].y, E[2].x};                                   \
    const v2f o2_ = (v2f){E[2].y, E[3].x};                                   \
    const v2f o3_ = (v2f){E[3].y, E[4].x};                                   \
    const v2f o4_ = (v2f){E[4].y, E[5].x};                                   \
    const v2f o5_ = (v2f){E[5].y, E[6].x};                                   \
    _Pragma("unroll") for (int t = 0; t < 8; ++t) {                          \
      if (t <= (K) && t + 6 >= (K)) { /* SE row a = K-t in 0..6 */           \
        ONEOUT(t, K, 0, o0_, o1_, o2_, E[3].y);                              \
        ONEOUT(t, K, 1, E[1], E[2], E[3], E[4].x);                           \
        ONEOUT(t, K, 2, o1_, o2_, o3_, E[4].y);                              \
        ONEOUT(t, K, 3, E[2], E[3], E[4], E[5].x);                           \
        ONEOUT(t, K, 4, o2_, o3_, o4_, E[5].y);                              \
        ONEOUT(t, K, 5, E[3], E[4], E[5], E[6].x);                           \
        ONEOUT(t, K, 6, o3_, o4_, o5_, E[6].y);                              \
        ONEOUT(t, K, 7, E[4], E[5], E[6], E[7].x);                           \
      }                                                                      \
    }                                                                        \
  }

#define STOREROW(T)                                                          \
  {                                                                          \
    float* orow_ = op + (ptrdiff_t)(row0 + (T)) * WW + col0;                 \
    *reinterpret_cast<float4*>(orow_) =                                      \
        make_float4(acc[T][0], acc[T][1], acc[T][2], acc[T][3]);             \
    *reinterpret_cast<float4*>(orow_ + 4) =                                  \
        make_float4(acc[T][4], acc[T][5], acc[T][6], acc[T][7]);             \
  }

__global__ __launch_bounds__(256) void dilate7(const float* __restrict__ x,
                                               const float* __restrict__ wg,
                                               float* __restrict__ out) {
  const int tid = threadIdx.x;
  const int lc = tid & 31;                        // 32 thread-cols
  const int tr = tid >> 5;                        // 8 thread-rows
  const int col0 = blockIdx.x * 256 + lc * 8;     // output col base (mult 8)
  const int row0 = blockIdx.y * 64 + tr * 8;      // output row base

  const size_t plane_off = (size_t)blockIdx.z * (size_t)(HH * WW);
  const float* xp = x + plane_off;
  float* op = out + plane_off;

  // Weights -> SGPRs (uniform loads), packed pairs.
  float wv[49];
#pragma unroll
  for (int i = 0; i < 49; ++i)
    wv[i] = __int_as_float(__builtin_amdgcn_readfirstlane(__float_as_int(wg[i])));
  v2f w2[7][3];
  float w6[7];
#pragma unroll
  for (int a = 0; a < 7; ++a) {
    w2[a][0] = (v2f){wv[7 * a + 0], wv[7 * a + 1]};
    w2[a][1] = (v2f){wv[7 * a + 2], wv[7 * a + 3]};
    w2[a][2] = (v2f){wv[7 * a + 4], wv[7 * a + 5]};
    w6[a] = wv[7 * a + 6];
  }

  const float* zp = &ZROW[0];
  const bool okL = (col0 >= 4);        // false only for global col0 == 0
  const bool okR = (col0 + 16 <= WW);  // false only for global col0 == 504

  float acc[8][8];                     // first write at K==t, no init needed
  v2f eA[8], eB[8];

  // 1-deep pipeline: load row K+1 while computing row K; store at K=t+6.
  LOADROW(eA, 0);
  LOADROW(eB, 1);   COMPROW(eA, 0);
  LOADROW(eA, 2);   COMPROW(eB, 1);
  LOADROW(eB, 3);   COMPROW(eA, 2);
  LOADROW(eA, 4);   COMPROW(eB, 3);
  LOADROW(eB, 5);   COMPROW(eA, 4);
  LOADROW(eA, 6);   COMPROW(eB, 5);
  LOADROW(eB, 7);   COMPROW(eA, 6);   STOREROW(0);
  LOADROW(eA, 8);   COMPROW(eB, 7);   STOREROW(1);
  LOADROW(eB, 9);   COMPROW(eA, 8);   STOREROW(2);
  LOADROW(eA, 10);  COMPROW(eB, 9);   STOREROW(3);
  LOADROW(eB, 11);  COMPROW(eA, 10);  STOREROW(4);
  LOADROW(eA, 12);  COMPROW(eB, 11);  STOREROW(5);
  LOADROW(eB, 13);  COMPROW(eA, 12);  STOREROW(6);
  COMPROW(eB, 13);  STOREROW(7);
}

extern "C" void kernel_launch(void* const* d_in, const int* in_sizes, int n_in,
                              void* d_out, int out_size, void* d_ws, size_t ws_size,
                              hipStream_t stream) {
  const float* x = (const float*)d_in[0];
  const float* w = (const float*)d_in[1];
  float* out = (float*)d_out;
  const int planes = in_sizes[0] / (HH * WW);   // 8*8 = 64
  dim3 grid(2, 8, planes);                      // 256x64 tile -> exact cover
  dilate7<<<grid, dim3(256, 1, 1), 0, stream>>>(x, w, out);
}

// Round 15
// 40.062 us; speedup vs baseline: 1.0789x; 1.0789x over previous
//
#include <hip/hip_runtime.h>

// Grayscale morphological dilation, 7x7 additive SE, zero 'same' padding:
//   out[p, i, j] = max_{a,b in 0..6} ( xz(p, i+a-3, j+b-3) + w[a,b] )
//
// FINAL (= R8, best measured 40.0us): 4-wide x 8-tall thread tile, block
// 256 = 64 thread-cols x 4 waves -> 256x32 block tile, grid (2,16,64) =
// 2048 blocks = 8 blocks/CU (max TLP, 32 waves/CU). Wave-uniform scalar
// row base with zero-row s_cselect (saddr loads); per-lane zero-page
// cndmask only for the 2 edge chunks; weights in SGPRs via readfirstlane;
// explicit v_max3_f32 tree (3 max3 + 1 max per output per SE-row);
// 1-deep prefetch; literal indices everywhere (no scratch).
//
// R15 hardening: ZROW sized 520 so the row-OOB path (zrb + col0 - 4 ..
// + 7, col0 up to 508) stays inside the zero array. R8 read past a
// 16-float array and passed only because trailing .rodata was zero.
//
// Measured across R7-R14: duration tracks total HBM-path bytes at
// ~3.25 TB/s effective; R8's 129.8 MB is the irreducible floor (input
// read once + output written once) and VALUBusy 77-80% is simultaneously
// at the practical issue ceiling -> balanced kernel.

#define HH 512
#define WW 512

__device__ __align__(16) const float ZROW[520] = {};  // zero region

__device__ __forceinline__ float max3f(float a, float b, float c) {
  float d;
  asm("v_max3_f32 %0, %1, %2, %3" : "=v"(d) : "v"(a), "v"(b), "v"(c));
  return d;
}

#define LOADROW(RV, K)                                                       \
  {                                                                          \
    const int r_ = row0 - 3 + (K);              /* scalar */                 \
    const float* rb_ = ((unsigned)r_ < (unsigned)HH)                         \
                           ? (xp + (ptrdiff_t)r_ * WW)                       \
                           : zrb;               /* s_cselect_b64 */          \
    const float* p0_ = okL ? rb_ + col0 - 4 : &ZROW[0];                      \
    const float* p2_ = okR ? rb_ + col0 + 4 : &ZROW[0];                      \
    float4 v0_ = *reinterpret_cast<const float4*>(p0_);                      \
    float4 v1_ = *reinterpret_cast<const float4*>(rb_ + col0);               \
    float4 v2_ = *reinterpret_cast<const float4*>(p2_);                      \
    RV[0] = v0_.x;  RV[1] = v0_.y;  RV[2] = v0_.z;  RV[3] = v0_.w;           \
    RV[4] = v1_.x;  RV[5] = v1_.y;  RV[6] = v1_.z;  RV[7] = v1_.w;           \
    RV[8] = v2_.x;  RV[9] = v2_.y;  RV[10] = v2_.z; RV[11] = v2_.w;          \
  }

// K is a literal at every expansion site; all indices fold at compile time.
#define COMPROW(RV, K)                                                       \
  {                                                                          \
    _Pragma("unroll") for (int t = 0; t < 8; ++t) {                          \
      if (t <= (K) && t + 6 >= (K)) { /* SE row a = K-t in 0..6 */           \
        const int a_ = (K) - t;                                              \
        _Pragma("unroll") for (int j = 0; j < 4; ++j) {                      \
          /* tap b: input col col0+j+b-3 -> RV[j+b+1] */                     \
          const float c0_ = RV[j + 1] + wv[a_ * 7 + 0];                      \
          const float c1_ = RV[j + 2] + wv[a_ * 7 + 1];                      \
          const float c2_ = RV[j + 3] + wv[a_ * 7 + 2];                      \
          const float c3_ = RV[j + 4] + wv[a_ * 7 + 3];                      \
          const float c4_ = RV[j + 5] + wv[a_ * 7 + 4];                      \
          const float c5_ = RV[j + 6] + wv[a_ * 7 + 5];                      \
          const float c6_ = RV[j + 7] + wv[a_ * 7 + 6];                      \
          const float t1_ = max3f(c0_, c1_, c2_);                            \
          const float t2_ = max3f(c3_, c4_, c5_);                            \
          acc[t][j] = ((K) == t)                                             \
                          ? max3f(t1_, t2_, c6_)          /* first touch */  \
                          : max3f(t1_, t2_, fmaxf(c6_, acc[t][j]));          \
        }                                                                    \
      }                                                                      \
    }                                                                        \
  }

#define STOREROW(T)                                                          \
  {                                                                          \
    float* orow_ = op + (ptrdiff_t)(row0 + (T)) * WW + col0;                 \
    *reinterpret_cast<float4*>(orow_) =                                      \
        make_float4(acc[T][0], acc[T][1], acc[T][2], acc[T][3]);             \
  }

__global__ __launch_bounds__(256) void dilate7(const float* __restrict__ x,
                                               const float* __restrict__ wg,
                                               float* __restrict__ out) {
  const int tid = threadIdx.x;
  const int lc = tid & 63;                          // 64 thread-cols per wave
  const int col0 = blockIdx.x * 256 + lc * 4;       // output col base (mult 4)
  // tid>>6 is the wave id -> row0 is wave-uniform; force it scalar.
  const int row0 =
      __builtin_amdgcn_readfirstlane(blockIdx.y * 32 + (tid >> 6) * 8);

  const size_t plane_off = (size_t)blockIdx.z * (size_t)(HH * WW);
  const float* xp = x + plane_off;
  float* op = out + plane_off;

  // Weights -> SGPRs (uniform loads).
  float wv[49];
#pragma unroll
  for (int i = 0; i < 49; ++i)
    wv[i] = __int_as_float(__builtin_amdgcn_readfirstlane(__float_as_int(wg[i])));

  const float* zrb = &ZROW[4];         // row base when the row is OOB
  const bool okL = (col0 >= 4);        // false only for global col0 == 0
  const bool okR = (col0 + 8 <= WW);   // false only for global col0 == 508

  float acc[8][4];                     // first write at K==t, no init needed
  float rvA[12], rvB[12];

  // 1-deep pipeline: load row K+1 while computing row K.
  LOADROW(rvA, 0);
  LOADROW(rvB, 1);   COMPROW(rvA, 0);
  LOADROW(rvA, 2);   COMPROW(rvB, 1);
  LOADROW(rvB, 3);   COMPROW(rvA, 2);
  LOADROW(rvA, 4);   COMPROW(rvB, 3);
  LOADROW(rvB, 5);   COMPROW(rvA, 4);
  LOADROW(rvA, 6);   COMPROW(rvB, 5);
  LOADROW(rvB, 7);   COMPROW(rvA, 6);   STOREROW(0);
  LOADROW(rvA, 8);   COMPROW(rvB, 7);   STOREROW(1);
  LOADROW(rvB, 9);   COMPROW(rvA, 8);   STOREROW(2);
  LOADROW(rvA, 10);  COMPROW(rvB, 9);   STOREROW(3);
  LOADROW(rvB, 11);  COMPROW(rvA, 10);  STOREROW(4);
  LOADROW(rvA, 12);  COMPROW(rvB, 11);  STOREROW(5);
  LOADROW(rvB, 13);  COMPROW(rvA, 12);  STOREROW(6);
  COMPROW(rvB, 13);  STOREROW(7);
}

extern "C" void kernel_launch(void* const* d_in, const int* in_sizes, int n_in,
                              void* d_out, int out_size, void* d_ws, size_t ws_size,
                              hipStream_t stream) {
  const float* x = (const float*)d_in[0];
  const float* w = (const float*)d_in[1];
  float* out = (float*)d_out;
  const int planes = in_sizes[0] / (HH * WW);   // 8*8 = 64
  dim3 grid(2, 16, planes);                     // 256x32 tile -> exact cover
  dilate7<<<grid, dim3(256, 1, 1), 0, stream>>>(x, w, out);
}